// Round 4
// baseline (4410.460 us; speedup 1.0000x reference)
//
#include <hip/hip_runtime.h>
#include <math.h>

// ---------------------------------------------------------------------------
// sLSTM block, round 4: scan fixed (no VGPR spill, (gate,channel) threads,
// minimal DS ops). FFN = bf16 MFMA (unchanged from round 3).
//   1. cvt_w ×2          : W1 -> w1b [4096][1024] bf16, W2 -> w2b [1024][2048]
//   2. ln_stats(x)       : mu1, rs1
//   3. ×8: proj_gemm(fp32, LN1 inline) -> proj chunk ; scan_chunk -> y(=d_out)
//   4. ln_stats(y)       : mu2, rs2
//   5. ×2: ff1_gemm (bf16 MFMA, LN2+gelu fused) -> g bf16 (32MB, aliases proj)
//          ff2_gemm (bf16 MFMA, bias+residual fused, in-place on d_out)
// Workspace (floats): r0 32MB | state 128KB | mu/rs 256KB | w1b 8MB | w2b 4MB
// ---------------------------------------------------------------------------

#define D_MODEL 1024
#define NHEAD   8
#define DPH     128
#define DFF     2048
#define BATCH   8
#define SEQ     2048
#define NROWS   (BATCH * SEQ)   // 16384
#define CHUNK_L 256             // scan steps per chunk (8 chunks)
#define ROWCH   8192            // FFN rows per chunk (2 chunks)
#define LN_EPS  1e-5f

typedef __attribute__((ext_vector_type(8))) short short8;
typedef __attribute__((ext_vector_type(4))) float f32x4;

__device__ __forceinline__ float gelu_exact(float x) {
  return 0.5f * x * (1.0f + erff(x * 0.70710678118654752440f));
}

__device__ __forceinline__ unsigned short f2bf(float f) {
  union { float f; unsigned int u; } v; v.f = f;
  unsigned int r = v.u + 0x7fffu + ((v.u >> 16) & 1u);
  return (unsigned short)(r >> 16);
}

// --------------------- per-row LN stats (mu, rstd) --------------------------
__global__ __launch_bounds__(256) void ln_stats_kernel(
    const float* __restrict__ in, float* __restrict__ mu_out,
    float* __restrict__ rs_out) {
  const int row = blockIdx.x, tid = threadIdx.x;
  const float4 v = ((const float4*)(in + (size_t)row * D_MODEL))[tid];
  float s  = v.x + v.y + v.z + v.w;
  float s2 = v.x*v.x + v.y*v.y + v.z*v.z + v.w*v.w;
  #pragma unroll
  for (int m = 1; m < 64; m <<= 1) { s += __shfl_xor(s, m, 64); s2 += __shfl_xor(s2, m, 64); }
  __shared__ float sa[4], sb[4];
  if ((tid & 63) == 0) { sa[tid >> 6] = s; sb[tid >> 6] = s2; }
  __syncthreads();
  if (tid == 0) {
    const float S  = sa[0] + sa[1] + sa[2] + sa[3];
    const float S2 = sb[0] + sb[1] + sb[2] + sb[3];
    const float mu = S * (1.0f / D_MODEL);
    const float var = S2 * (1.0f / D_MODEL) - mu * mu;
    mu_out[row] = mu;
    rs_out[row] = rsqrtf(var + LN_EPS);
  }
}

// -------------- weight convert+transpose: [K][N] f32 -> [N][K] bf16 ---------
__global__ __launch_bounds__(256) void cvt_w(
    const float* __restrict__ src, short* __restrict__ dst, int K, int N) {
  __shared__ float tile[64][68];
  const int n0 = blockIdx.x * 64;
  const int k0 = blockIdx.y * 64;
  const int tid = threadIdx.x;
  #pragma unroll
  for (int i = 0; i < 16; ++i) {
    const int e = i * 256 + tid;
    const int kk = e >> 6, nn = e & 63;
    tile[kk][nn] = src[(size_t)(k0 + kk) * N + n0 + nn];
  }
  __syncthreads();
  #pragma unroll
  for (int i = 0; i < 2; ++i) {
    const int e = i * 256 + tid;
    const int nn = e >> 3, kc = (e & 7) * 8;
    short8 s;
    #pragma unroll
    for (int j = 0; j < 8; ++j) s[j] = (short)f2bf(tile[kc + j][nn]);
    *(short8*)(dst + (size_t)(n0 + nn) * K + k0 + kc) = s;
  }
}

// --------------------------- head projection GEMM --------------------------
// chunk of 256 steps: M-space = (l-l0)*8+b in [0,2048). per head h:
// (2048 x 128) @ (128 x 512). BM=64, BN=128, BK=64. LN1 applied on A-load.
__global__ __launch_bounds__(256) void proj_gemm(
    const float* __restrict__ x, const float* __restrict__ mu1,
    const float* __restrict__ rs1, const float* __restrict__ ln1w,
    const float* __restrict__ ln1b, const float* __restrict__ ihw,
    const float* __restrict__ ihb, float* __restrict__ proj, int l0) {
  __shared__ __align__(16) float As[64][68];
  __shared__ __align__(16) float Bs[64][128];
  const int h  = blockIdx.z;
  const int n0 = blockIdx.y * 128;
  const int m0 = blockIdx.x * 64;
  const int tid = threadIdx.x;
  const int tm = (tid >> 5) << 3;
  const int tn = (tid & 31) << 2;
  float acc[8][4] = {};
  const float* Bb = ihw + (size_t)h * DPH * 512;
  for (int k0 = 0; k0 < DPH; k0 += 64) {
    #pragma unroll
    for (int i = 0; i < 4; ++i) {
      int idx = tid + i * 256;
      int r = idx >> 4, kk = (idx & 15) << 2;
      const int rowm = m0 + r;
      const int l = l0 + (rowm >> 3), b = rowm & 7;
      const int grow = b * SEQ + l;
      const float4 v = *(const float4*)(x + (size_t)grow * D_MODEL + h * DPH + k0 + kk);
      const float mu = mu1[grow], rs = rs1[grow];
      const float4 wv = *(const float4*)(ln1w + h * DPH + k0 + kk);
      const float4 bv = *(const float4*)(ln1b + h * DPH + k0 + kk);
      float4 o;
      o.x = (v.x - mu) * rs * wv.x + bv.x;
      o.y = (v.y - mu) * rs * wv.y + bv.y;
      o.z = (v.z - mu) * rs * wv.z + bv.z;
      o.w = (v.w - mu) * rs * wv.w + bv.w;
      *(float4*)&As[r][kk] = o;
    }
    #pragma unroll
    for (int i = 0; i < 8; ++i) {
      int idx = tid + i * 256;
      int kk = idx >> 5, nn = (idx & 31) << 2;
      *(float4*)&Bs[kk][nn] = *(const float4*)(Bb + (size_t)(k0 + kk) * 512 + n0 + nn);
    }
    __syncthreads();
    #pragma unroll 4
    for (int kk = 0; kk < 64; ++kk) {
      float a[8];
      #pragma unroll
      for (int i = 0; i < 8; ++i) a[i] = As[tm + i][kk];
      const float4 bv = *(const float4*)&Bs[kk][tn];
      #pragma unroll
      for (int i = 0; i < 8; ++i) {
        acc[i][0] += a[i] * bv.x; acc[i][1] += a[i] * bv.y;
        acc[i][2] += a[i] * bv.z; acc[i][3] += a[i] * bv.w;
      }
    }
    __syncthreads();
  }
  const float4 bias = *(const float4*)(ihb + h * 512 + n0 + tn);
  #pragma unroll
  for (int i = 0; i < 8; ++i) {
    const int rowm = m0 + tm + i;
    float4 o;
    o.x = acc[i][0] + bias.x; o.y = acc[i][1] + bias.y;
    o.z = acc[i][2] + bias.z; o.w = acc[i][3] + bias.w;
    *(float4*)(proj + ((size_t)rowm * NHEAD + h) * 512 + n0 + tn) = o;
  }
}

// ------------------------------- sLSTM scan --------------------------------
// 512 threads = 4 gates x 128 channels. Thread (g,ch) owns output column
// g*128+ch of the recurrent matvec with FULL K=128 in registers (128 VGPRs,
// guaranteed resident by __launch_bounds__(512,2)). h broadcast-read from LDS
// (uniform address = free); gate exchange via p_lds[4][128]; gate math
// replicated over g (bit-identical); headLN+residual fused, y -> d_out.
__global__ __launch_bounds__(512, 2) void scan_chunk(
    const float* __restrict__ proj, const float* __restrict__ hhw,
    const float* __restrict__ x, const float* __restrict__ hnw,
    const float* __restrict__ hnb, float* __restrict__ state,
    float* __restrict__ y, int l0) {
  const int bh = blockIdx.x, b = bh >> 3, h = bh & 7;
  const int tid = threadIdx.x;
  const int g  = tid >> 7;       // gate (wave-uniform: waves 2g, 2g+1)
  const int ch = tid & 127;      // channel
  __shared__ __align__(16) float h_lds[128];
  __shared__ float p_lds[4][128];
  __shared__ __align__(16) float red[4];   // {s_h0, s2_h0, s_h1, s2_h1}
  // hh_w column (g*128+ch), full K, in registers.
  float w[128];
  #pragma unroll
  for (int k = 0; k < 128; ++k) w[k] = hhw[(size_t)k * 512 + g * 128 + ch];
  float c, nrm, m;
  if (l0 == 0) {
    c = 0.0f; nrm = 0.0f; m = -1e30f;
    if (g == 0) h_lds[ch] = 0.0f;
  } else {
    c   = state[bh * 128 + ch];
    nrm = state[8192  + bh * 128 + ch];
    m   = state[16384 + bh * 128 + ch];
    if (g == 0) h_lds[ch] = state[24576 + bh * 128 + ch];
  }
  const float hw = hnw[ch], hb = hnb[ch];
  __syncthreads();
  const size_t pstep = (size_t)BATCH * NHEAD * 512;   // 32768
  const float* prow = proj + ((size_t)b * NHEAD + h) * 512 + g * 128 + ch;
  const float* xrow = x + ((size_t)(b * SEQ + l0)) * D_MODEL + h * DPH + ch;
  float*       yrow = y + ((size_t)(b * SEQ + l0)) * D_MODEL + h * DPH + ch;
  float pv = prow[0];
  float xv = (g == 0) ? xrow[0] : 0.0f;
  float hv = 0.0f;
  for (int t = 0; t < CHUNK_L; ++t) {
    // prefetch next step's inputs (latency hidden under the matvec)
    const float pvn = (t + 1 < CHUNK_L) ? prow[(size_t)(t + 1) * pstep] : 0.0f;
    const float xvn = (g == 0 && t + 1 < CHUNK_L) ? xrow[(size_t)(t + 1) * D_MODEL] : 0.0f;
    // matvec: 4 independent 32-FMA chains; h reads are wave-uniform broadcasts
    float a0 = 0.0f, a1 = 0.0f, a2 = 0.0f, a3 = 0.0f;
    const float4* h4 = (const float4*)h_lds;
    #pragma unroll
    for (int k4 = 0; k4 < 8; ++k4) {
      const float4 hk = h4[k4];
      a0 += hk.x * w[4*k4]    + hk.y * w[4*k4+1]  + hk.z * w[4*k4+2]  + hk.w * w[4*k4+3];
    }
    #pragma unroll
    for (int k4 = 8; k4 < 16; ++k4) {
      const float4 hk = h4[k4];
      a1 += hk.x * w[4*k4]    + hk.y * w[4*k4+1]  + hk.z * w[4*k4+2]  + hk.w * w[4*k4+3];
    }
    #pragma unroll
    for (int k4 = 16; k4 < 24; ++k4) {
      const float4 hk = h4[k4];
      a2 += hk.x * w[4*k4]    + hk.y * w[4*k4+1]  + hk.z * w[4*k4+2]  + hk.w * w[4*k4+3];
    }
    #pragma unroll
    for (int k4 = 24; k4 < 32; ++k4) {
      const float4 hk = h4[k4];
      a3 += hk.x * w[4*k4]    + hk.y * w[4*k4+1]  + hk.z * w[4*k4+2]  + hk.w * w[4*k4+3];
    }
    p_lds[g][ch] = pv + ((a0 + a1) + (a2 + a3));
    __syncthreads();                               // B1: all p ready
    // gate math, replicated across g (identical inputs -> identical results)
    const float iv   = p_lds[0][ch];
    const float fv   = p_lds[1][ch];
    const float zraw = p_lds[2][ch];
    const float oraw = p_lds[3][ch];
    const float zv = 1.0f - 2.0f / (__expf(2.0f * zraw) + 1.0f);
    const float ov = 1.0f / (1.0f + __expf(-oraw));
    const float lf = fminf(fv, 0.0f) - __logf(1.0f + __expf(-fabsf(fv)));
    const float ft = lf + m;
    const float mn = fmaxf(ft, iv);
    const float is = __expf(iv - mn);
    const float fs = __expf(ft - mn);
    c = fs * c + is * zv;
    nrm = fs * nrm + is;
    m = mn;
    hv = ov * (c / nrm);
    if (g == 0) {
      h_lds[ch] = hv;
      // headLN partials: wave 0 covers ch 0..63, wave 1 covers 64..127
      float s = hv, s2 = hv * hv;
      #pragma unroll
      for (int mm = 1; mm < 64; mm <<= 1) { s += __shfl_xor(s, mm); s2 += __shfl_xor(s2, mm); }
      if ((tid & 63) == 0) { red[(ch >> 6) * 2] = s; red[(ch >> 6) * 2 + 1] = s2; }
    }
    __syncthreads();                               // B2: h + red ready
    if (g == 0) {
      const float4 r = *(const float4*)red;        // broadcast
      const float S = r.x + r.z, S2 = r.y + r.w;
      const float mu = S * (1.0f / DPH);
      const float var = S2 * (1.0f / DPH) - mu * mu;
      const float rstd = rsqrtf(var + LN_EPS);
      yrow[(size_t)t * D_MODEL] = (hv - mu) * rstd * hw + hb + xv;
    }
    pv = pvn; xv = xvn;
  }
  if (g == 0) {
    state[bh * 128 + ch]         = c;
    state[8192  + bh * 128 + ch] = nrm;
    state[16384 + bh * 128 + ch] = m;
    state[24576 + bh * 128 + ch] = hv;
  }
}

// ------------------------------ FF1 (bf16 MFMA) ------------------------------
__global__ __launch_bounds__(256) void ff1_gemm(
    const float* __restrict__ y, const float* __restrict__ mu2,
    const float* __restrict__ rs2, const float* __restrict__ ln2w,
    const float* __restrict__ ln2b, const short* __restrict__ w1b,
    const float* __restrict__ b1, short* __restrict__ g, int row0) {
  __shared__ short As[128 * 64];
  __shared__ short Bs1[128 * 64];
  __shared__ short Bs2[128 * 64];
  const int tid = threadIdx.x;
  const int m0 = blockIdx.x * 128;
  const int n0 = blockIdx.y * 128;
  const int lane = tid & 63;
  const int wid = tid >> 6, wr = wid >> 1, wc = wid & 1;
  f32x4 acc1[4][4], acc2[4][4];
  #pragma unroll
  for (int i = 0; i < 4; ++i)
    #pragma unroll
    for (int j = 0; j < 4; ++j) { acc1[i][j] = (f32x4)0.0f; acc2[i][j] = (f32x4)0.0f; }
  for (int k0 = 0; k0 < D_MODEL; k0 += 64) {
    #pragma unroll
    for (int i = 0; i < 4; ++i) {
      const int cidx = tid + i * 256;
      const int r = cidx >> 3, c8 = cidx & 7;
      const int grow = row0 + m0 + r;
      const float* src = y + (size_t)grow * D_MODEL + k0 + c8 * 8;
      const float4 v0 = *(const float4*)src;
      const float4 v1 = *(const float4*)(src + 4);
      const float mu = mu2[grow], rs = rs2[grow];
      const float4 w0 = *(const float4*)(ln2w + k0 + c8 * 8);
      const float4 w1 = *(const float4*)(ln2w + k0 + c8 * 8 + 4);
      const float4 bb0 = *(const float4*)(ln2b + k0 + c8 * 8);
      const float4 bb1 = *(const float4*)(ln2b + k0 + c8 * 8 + 4);
      short8 s;
      s[0] = (short)f2bf((v0.x - mu) * rs * w0.x + bb0.x);
      s[1] = (short)f2bf((v0.y - mu) * rs * w0.y + bb0.y);
      s[2] = (short)f2bf((v0.z - mu) * rs * w0.z + bb0.z);
      s[3] = (short)f2bf((v0.w - mu) * rs * w0.w + bb0.w);
      s[4] = (short)f2bf((v1.x - mu) * rs * w1.x + bb1.x);
      s[5] = (short)f2bf((v1.y - mu) * rs * w1.y + bb1.y);
      s[6] = (short)f2bf((v1.z - mu) * rs * w1.z + bb1.z);
      s[7] = (short)f2bf((v1.w - mu) * rs * w1.w + bb1.w);
      *(short8*)&As[r * 64 + ((c8 ^ (r & 7)) << 3)] = s;
    }
    #pragma unroll
    for (int i = 0; i < 4; ++i) {
      const int cidx = tid + i * 256;
      const int r = cidx >> 3, c8 = cidx & 7;
      const short8 sv1 = *(const short8*)(w1b + (size_t)(n0 + r) * D_MODEL + k0 + c8 * 8);
      const short8 sv2 = *(const short8*)(w1b + (size_t)(DFF + n0 + r) * D_MODEL + k0 + c8 * 8);
      const int off = r * 64 + ((c8 ^ (r & 7)) << 3);
      *(short8*)&Bs1[off] = sv1;
      *(short8*)&Bs2[off] = sv2;
    }
    __syncthreads();
    #pragma unroll
    for (int ks = 0; ks < 2; ++ks) {
      short8 af[4], b1f[4], b2f[4];
      #pragma unroll
      for (int mf = 0; mf < 4; ++mf) {
        const int row = wr * 64 + mf * 16 + (lane & 15);
        const int c8 = ks * 4 + (lane >> 4);
        af[mf] = *(const short8*)&As[row * 64 + ((c8 ^ (row & 7)) << 3)];
      }
      #pragma unroll
      for (int nf = 0; nf < 4; ++nf) {
        const int row = wc * 64 + nf * 16 + (lane & 15);
        const int c8 = ks * 4 + (lane >> 4);
        const int off = row * 64 + ((c8 ^ (row & 7)) << 3);
        b1f[nf] = *(const short8*)&Bs1[off];
        b2f[nf] = *(const short8*)&Bs2[off];
      }
      #pragma unroll
      for (int mf = 0; mf < 4; ++mf)
        #pragma unroll
        for (int nf = 0; nf < 4; ++nf) {
          acc1[mf][nf] = __builtin_amdgcn_mfma_f32_16x16x32_bf16(af[mf], b1f[nf], acc1[mf][nf], 0, 0, 0);
          acc2[mf][nf] = __builtin_amdgcn_mfma_f32_16x16x32_bf16(af[mf], b2f[nf], acc2[mf][nf], 0, 0, 0);
        }
    }
    __syncthreads();
  }
  #pragma unroll
  for (int nf = 0; nf < 4; ++nf) {
    const int col = n0 + wc * 64 + nf * 16 + (lane & 15);
    const float bx1 = b1[col], bx2 = b1[DFF + col];
    #pragma unroll
    for (int mf = 0; mf < 4; ++mf) {
      const int rbase = m0 + wr * 64 + mf * 16 + ((lane >> 4) << 2);
      #pragma unroll
      for (int rr = 0; rr < 4; ++rr) {
        const float x1 = acc1[mf][nf][rr] + bx1;
        const float x2 = acc2[mf][nf][rr] + bx2;
        g[(size_t)(rbase + rr) * DFF + col] = (short)f2bf(x1 * gelu_exact(x2));
      }
    }
  }
}

// ----------------- FF2 (bf16 MFMA) + bias + residual, in place --------------
__global__ __launch_bounds__(256) void ff2_gemm(
    const short* __restrict__ g, const short* __restrict__ w2b,
    const float* __restrict__ b2, float* __restrict__ out, int row0) {
  __shared__ short As[128 * 64];
  __shared__ short Bs[128 * 64];
  const int tid = threadIdx.x;
  const int m0 = blockIdx.x * 128;
  const int n0 = blockIdx.y * 128;
  const int lane = tid & 63;
  const int wid = tid >> 6, wr = wid >> 1, wc = wid & 1;
  f32x4 acc[4][4];
  #pragma unroll
  for (int i = 0; i < 4; ++i)
    #pragma unroll
    for (int j = 0; j < 4; ++j) acc[i][j] = (f32x4)0.0f;
  for (int k0 = 0; k0 < DFF; k0 += 64) {
    #pragma unroll
    for (int i = 0; i < 4; ++i) {
      const int cidx = tid + i * 256;
      const int r = cidx >> 3, c8 = cidx & 7;
      const int off = r * 64 + ((c8 ^ (r & 7)) << 3);
      *(short8*)&As[off] = *(const short8*)(g + (size_t)(m0 + r) * DFF + k0 + c8 * 8);
      *(short8*)&Bs[off] = *(const short8*)(w2b + (size_t)(n0 + r) * DFF + k0 + c8 * 8);
    }
    __syncthreads();
    #pragma unroll
    for (int ks = 0; ks < 2; ++ks) {
      short8 af[4], bf[4];
      #pragma unroll
      for (int mf = 0; mf < 4; ++mf) {
        const int row = wr * 64 + mf * 16 + (lane & 15);
        const int c8 = ks * 4 + (lane >> 4);
        af[mf] = *(const short8*)&As[row * 64 + ((c8 ^ (row & 7)) << 3)];
      }
      #pragma unroll
      for (int nf = 0; nf < 4; ++nf) {
        const int row = wc * 64 + nf * 16 + (lane & 15);
        const int c8 = ks * 4 + (lane >> 4);
        bf[nf] = *(const short8*)&Bs[row * 64 + ((c8 ^ (row & 7)) << 3)];
      }
      #pragma unroll
      for (int mf = 0; mf < 4; ++mf)
        #pragma unroll
        for (int nf = 0; nf < 4; ++nf)
          acc[mf][nf] = __builtin_amdgcn_mfma_f32_16x16x32_bf16(af[mf], bf[nf], acc[mf][nf], 0, 0, 0);
    }
    __syncthreads();
  }
  #pragma unroll
  for (int nf = 0; nf < 4; ++nf) {
    const int col = n0 + wc * 64 + nf * 16 + (lane & 15);
    const float bias = b2[col];
    #pragma unroll
    for (int mf = 0; mf < 4; ++mf) {
      const int rbase = row0 + m0 + wr * 64 + mf * 16 + ((lane >> 4) << 2);
      #pragma unroll
      for (int rr = 0; rr < 4; ++rr) {
        float* p = out + (size_t)(rbase + rr) * D_MODEL + col;
        *p = acc[mf][nf][rr] + bias + *p;
      }
    }
  }
}

// ------------------------------- launcher -----------------------------------
extern "C" void kernel_launch(void* const* d_in, const int* in_sizes, int n_in,
                              void* d_out, int out_size, void* d_ws, size_t ws_size,
                              hipStream_t stream) {
  const float* x    = (const float*)d_in[0];
  const float* ihw  = (const float*)d_in[1];
  const float* ihb  = (const float*)d_in[2];
  const float* hhw  = (const float*)d_in[3];
  const float* ln1w = (const float*)d_in[4];
  const float* ln1b = (const float*)d_in[5];
  const float* hnw  = (const float*)d_in[6];
  const float* hnb  = (const float*)d_in[7];
  const float* ln2w = (const float*)d_in[8];
  const float* ln2b = (const float*)d_in[9];
  const float* ffw1 = (const float*)d_in[10];
  const float* ffb1 = (const float*)d_in[11];
  const float* ffw2 = (const float*)d_in[12];
  const float* ffb2 = (const float*)d_in[13];

  float* ws    = (float*)d_ws;
  float* r0    = ws;                    // 8388608 floats: proj fp32 / g bf16
  float* state = ws + 8388608;          // 32768
  float* mu1   = ws + 8421376;
  float* rs1   = ws + 8437760;
  float* mu2   = ws + 8454144;
  float* rs2   = ws + 8470528;
  short* w1b   = (short*)(ws + 8486912);   // 4096x1024 bf16 (8 MB)
  short* w2b   = (short*)(ws + 10584064);  // 1024x2048 bf16 (4 MB)
  short* gb    = (short*)r0;               // 8192x2048 bf16 chunk (32 MB)
  float* out   = (float*)d_out;

  cvt_w<<<dim3(4096 / 64, 1024 / 64), 256, 0, stream>>>(ffw1, w1b, 1024, 4096);
  cvt_w<<<dim3(1024 / 64, 2048 / 64), 256, 0, stream>>>(ffw2, w2b, 2048, 1024);
  ln_stats_kernel<<<NROWS, 256, 0, stream>>>(x, mu1, rs1);
  for (int cidx = 0; cidx < SEQ / CHUNK_L; ++cidx) {
    const int l0 = cidx * CHUNK_L;
    proj_gemm<<<dim3(CHUNK_L * BATCH / 64, 512 / 128, NHEAD), 256, 0, stream>>>(
        x, mu1, rs1, ln1w, ln1b, ihw, ihb, r0, l0);
    scan_chunk<<<BATCH * NHEAD, 512, 0, stream>>>(r0, hhw, x, hnw, hnb, state, out, l0);
  }
  ln_stats_kernel<<<NROWS, 256, 0, stream>>>(out, mu2, rs2);
  for (int rc = 0; rc < NROWS / ROWCH; ++rc) {
    const int row0 = rc * ROWCH;
    ff1_gemm<<<dim3(ROWCH / 128, DFF / 128), 256, 0, stream>>>(
        out, mu2, rs2, ln2w, ln2b, w1b, ffb1, gb, row0);
    ff2_gemm<<<dim3(ROWCH / 128, D_MODEL / 128), 256, 0, stream>>>(
        gb, w2b, ffb2, out, row0);
  }
}

// Round 5
// 2949.703 us; speedup vs baseline: 1.4952x; 1.4952x over previous
//
#include <hip/hip_runtime.h>
#include <math.h>

// ---------------------------------------------------------------------------
// sLSTM block, round 5: scan matvec via packed-f16 v_dot2 (64 VGPR weights,
// no spill). FFN = bf16 MFMA (unchanged). Pipeline:
//   1. cvt_w ×2 (W1,W2 -> bf16 [n][k]) ; cvt_hh (hh_w -> packed f16 [k/2][512])
//   2. ln_stats(x) -> mu1, rs1
//   3. ×8: proj_gemm(fp32, LN1 inline) -> proj chunk ; scan_chunk -> y(=d_out)
//   4. ln_stats(y) -> mu2, rs2
//   5. ×2: ff1_gemm (bf16 MFMA, LN2+gelu fused) -> g bf16 ; ff2_gemm (in place)
// Workspace (floats): r0 32MB | state 128KB | mu/rs 256KB | w1b 8MB | w2b 4MB
//                     | hh2 128KB   (~44.6 MB)
// ---------------------------------------------------------------------------

#define D_MODEL 1024
#define NHEAD   8
#define DPH     128
#define DFF     2048
#define BATCH   8
#define SEQ     2048
#define NROWS   (BATCH * SEQ)   // 16384
#define CHUNK_L 256             // scan steps per chunk (8 chunks)
#define ROWCH   8192            // FFN rows per chunk (2 chunks)
#define LN_EPS  1e-5f

typedef __attribute__((ext_vector_type(8))) short short8;
typedef __attribute__((ext_vector_type(4))) float f32x4;
typedef __attribute__((ext_vector_type(2))) _Float16 h2f;
typedef __attribute__((ext_vector_type(8))) _Float16 h8f;
union H8U { h8f v; h2f p[4]; };

#if __has_builtin(__builtin_amdgcn_fdot2)
#define DOT2(a, b, c) __builtin_amdgcn_fdot2((a), (b), (c), false)
#else
__device__ __forceinline__ float DOT2(h2f a, h2f b, float c) {
  return c + (float)a.x * (float)b.x + (float)a.y * (float)b.y;
}
#endif

__device__ __forceinline__ float gelu_exact(float x) {
  return 0.5f * x * (1.0f + erff(x * 0.70710678118654752440f));
}

__device__ __forceinline__ unsigned short f2bf(float f) {
  union { float f; unsigned int u; } v; v.f = f;
  unsigned int r = v.u + 0x7fffu + ((v.u >> 16) & 1u);
  return (unsigned short)(r >> 16);
}

// --------------------- per-row LN stats (mu, rstd) --------------------------
__global__ __launch_bounds__(256) void ln_stats_kernel(
    const float* __restrict__ in, float* __restrict__ mu_out,
    float* __restrict__ rs_out) {
  const int row = blockIdx.x, tid = threadIdx.x;
  const float4 v = ((const float4*)(in + (size_t)row * D_MODEL))[tid];
  float s  = v.x + v.y + v.z + v.w;
  float s2 = v.x*v.x + v.y*v.y + v.z*v.z + v.w*v.w;
  #pragma unroll
  for (int m = 1; m < 64; m <<= 1) { s += __shfl_xor(s, m, 64); s2 += __shfl_xor(s2, m, 64); }
  __shared__ float sa[4], sb[4];
  if ((tid & 63) == 0) { sa[tid >> 6] = s; sb[tid >> 6] = s2; }
  __syncthreads();
  if (tid == 0) {
    const float S  = sa[0] + sa[1] + sa[2] + sa[3];
    const float S2 = sb[0] + sb[1] + sb[2] + sb[3];
    const float mu = S * (1.0f / D_MODEL);
    const float var = S2 * (1.0f / D_MODEL) - mu * mu;
    mu_out[row] = mu;
    rs_out[row] = rsqrtf(var + LN_EPS);
  }
}

// -------------- weight convert+transpose: [K][N] f32 -> [N][K] bf16 ---------
__global__ __launch_bounds__(256) void cvt_w(
    const float* __restrict__ src, short* __restrict__ dst, int K, int N) {
  __shared__ float tile[64][68];
  const int n0 = blockIdx.x * 64;
  const int k0 = blockIdx.y * 64;
  const int tid = threadIdx.x;
  #pragma unroll
  for (int i = 0; i < 16; ++i) {
    const int e = i * 256 + tid;
    const int kk = e >> 6, nn = e & 63;
    tile[kk][nn] = src[(size_t)(k0 + kk) * N + n0 + nn];
  }
  __syncthreads();
  #pragma unroll
  for (int i = 0; i < 2; ++i) {
    const int e = i * 256 + tid;
    const int nn = e >> 3, kc = (e & 7) * 8;
    short8 s;
    #pragma unroll
    for (int j = 0; j < 8; ++j) s[j] = (short)f2bf(tile[kc + j][nn]);
    *(short8*)(dst + (size_t)(n0 + nn) * K + k0 + kc) = s;
  }
}

// ---- hh_w [128][512] f32 -> packed f16 pairs hh2[k2][512], k2 = k/2 --------
__global__ __launch_bounds__(256) void cvt_hh(
    const float* __restrict__ hhw, h2f* __restrict__ hh2) {
  const int idx = blockIdx.x * 256 + threadIdx.x;   // 32768 total
  const int k2 = idx >> 9, j = idx & 511;
  h2f v;
  v.x = (_Float16)hhw[(size_t)(2 * k2) * 512 + j];
  v.y = (_Float16)hhw[(size_t)(2 * k2 + 1) * 512 + j];
  hh2[idx] = v;                                     // idx = k2*512 + j
}

// --------------------------- head projection GEMM --------------------------
// chunk of 256 steps: M-space = (l-l0)*8+b in [0,2048). per head h:
// (2048 x 128) @ (128 x 512). BM=64, BN=128, BK=64. LN1 applied on A-load.
__global__ __launch_bounds__(256) void proj_gemm(
    const float* __restrict__ x, const float* __restrict__ mu1,
    const float* __restrict__ rs1, const float* __restrict__ ln1w,
    const float* __restrict__ ln1b, const float* __restrict__ ihw,
    const float* __restrict__ ihb, float* __restrict__ proj, int l0) {
  __shared__ __align__(16) float As[64][68];
  __shared__ __align__(16) float Bs[64][128];
  const int h  = blockIdx.z;
  const int n0 = blockIdx.y * 128;
  const int m0 = blockIdx.x * 64;
  const int tid = threadIdx.x;
  const int tm = (tid >> 5) << 3;
  const int tn = (tid & 31) << 2;
  float acc[8][4] = {};
  const float* Bb = ihw + (size_t)h * DPH * 512;
  for (int k0 = 0; k0 < DPH; k0 += 64) {
    #pragma unroll
    for (int i = 0; i < 4; ++i) {
      int idx = tid + i * 256;
      int r = idx >> 4, kk = (idx & 15) << 2;
      const int rowm = m0 + r;
      const int l = l0 + (rowm >> 3), b = rowm & 7;
      const int grow = b * SEQ + l;
      const float4 v = *(const float4*)(x + (size_t)grow * D_MODEL + h * DPH + k0 + kk);
      const float mu = mu1[grow], rs = rs1[grow];
      const float4 wv = *(const float4*)(ln1w + h * DPH + k0 + kk);
      const float4 bv = *(const float4*)(ln1b + h * DPH + k0 + kk);
      float4 o;
      o.x = (v.x - mu) * rs * wv.x + bv.x;
      o.y = (v.y - mu) * rs * wv.y + bv.y;
      o.z = (v.z - mu) * rs * wv.z + bv.z;
      o.w = (v.w - mu) * rs * wv.w + bv.w;
      *(float4*)&As[r][kk] = o;
    }
    #pragma unroll
    for (int i = 0; i < 8; ++i) {
      int idx = tid + i * 256;
      int kk = idx >> 5, nn = (idx & 31) << 2;
      *(float4*)&Bs[kk][nn] = *(const float4*)(Bb + (size_t)(k0 + kk) * 512 + n0 + nn);
    }
    __syncthreads();
    #pragma unroll 4
    for (int kk = 0; kk < 64; ++kk) {
      float a[8];
      #pragma unroll
      for (int i = 0; i < 8; ++i) a[i] = As[tm + i][kk];
      const float4 bv = *(const float4*)&Bs[kk][tn];
      #pragma unroll
      for (int i = 0; i < 8; ++i) {
        acc[i][0] += a[i] * bv.x; acc[i][1] += a[i] * bv.y;
        acc[i][2] += a[i] * bv.z; acc[i][3] += a[i] * bv.w;
      }
    }
    __syncthreads();
  }
  const float4 bias = *(const float4*)(ihb + h * 512 + n0 + tn);
  #pragma unroll
  for (int i = 0; i < 8; ++i) {
    const int rowm = m0 + tm + i;
    float4 o;
    o.x = acc[i][0] + bias.x; o.y = acc[i][1] + bias.y;
    o.z = acc[i][2] + bias.z; o.w = acc[i][3] + bias.w;
    *(float4*)(proj + ((size_t)rowm * NHEAD + h) * 512 + n0 + tn) = o;
  }
}

// ------------------------------- sLSTM scan --------------------------------
// 512 threads = 4 gates x 128 channels. Thread (g,ch) owns output column
// tid = g*128+ch with FULL K=128 as 64 packed-f16 pairs (64 VGPRs -> fits the
// compiler's 128-VGPR budget, no spill). h lives in LDS as 128 f16 (256 B);
// matvec = 16 broadcast ds_read_b128 + 64 v_dot2_f32_f16 in 4 indep chains.
// Gate math + headLN + residual on g=0 waves only; y -> d_out directly.
__global__ __launch_bounds__(512, 2) void scan_chunk(
    const float* __restrict__ proj, const h2f* __restrict__ hh2,
    const float* __restrict__ x, const float* __restrict__ hnw,
    const float* __restrict__ hnb, float* __restrict__ state,
    float* __restrict__ y, int l0) {
  const int bh = blockIdx.x, b = bh >> 3, h = bh & 7;
  const int tid = threadIdx.x;
  const int g  = tid >> 7;       // gate (wave-uniform)
  const int ch = tid & 127;      // channel
  __shared__ __align__(16) _Float16 h16[128];   // 256 B
  __shared__ float p_lds[4][128];
  __shared__ __align__(16) float red[4];        // {s_lo, s2_lo, s_hi, s2_hi}
  // packed hh_w column tid: w2[k2] = (hh_w[2k2][tid], hh_w[2k2+1][tid]) as f16x2
  h2f w2[64];
  #pragma unroll
  for (int k2 = 0; k2 < 64; ++k2) w2[k2] = hh2[k2 * 512 + tid];  // coalesced
  float c, nrm, m, hv = 0.0f;
  if (l0 == 0) {
    c = 0.0f; nrm = 0.0f; m = -1e30f;
    if (g == 0) h16[ch] = (_Float16)0.0f;
  } else {
    c   = state[bh * 128 + ch];
    nrm = state[8192  + bh * 128 + ch];
    m   = state[16384 + bh * 128 + ch];
    if (g == 0) h16[ch] = (_Float16)state[24576 + bh * 128 + ch];
  }
  const float hw = hnw[ch], hb = hnb[ch];
  __syncthreads();
  const size_t pstep = (size_t)BATCH * NHEAD * 512;   // 32768
  const float* prow = proj + ((size_t)b * NHEAD + h) * 512 + tid;
  const float* xrow = x + ((size_t)(b * SEQ + l0)) * D_MODEL + h * DPH + ch;
  float*       yrow = y + ((size_t)(b * SEQ + l0)) * D_MODEL + h * DPH + ch;
  float pv = prow[0];
  float xv = (g == 0) ? xrow[0] : 0.0f;
  for (int t = 0; t < CHUNK_L; ++t) {
    // prefetch next step's inputs (latency hidden under the matvec)
    const float pvn = (t + 1 < CHUNK_L) ? prow[(size_t)(t + 1) * pstep] : 0.0f;
    const float xvn = (g == 0 && t + 1 < CHUNK_L) ? xrow[(size_t)(t + 1) * D_MODEL] : 0.0f;
    // matvec: 4 independent 16-dot2 chains; h reads are uniform-address
    // broadcasts (free); all indices compile-time after unroll.
    float a0 = 0.0f, a1 = 0.0f, a2 = 0.0f, a3 = 0.0f;
    const h8f* hp = (const h8f*)h16;   // 16 x (8 f16)
    #pragma unroll
    for (int i = 0; i < 4; ++i) {
      H8U u0, u1, u2, u3;
      u0.v = hp[i]; u1.v = hp[4 + i]; u2.v = hp[8 + i]; u3.v = hp[12 + i];
      #pragma unroll
      for (int e = 0; e < 4; ++e) {
        a0 = DOT2(u0.p[e], w2[     4 * i + e], a0);
        a1 = DOT2(u1.p[e], w2[16 + 4 * i + e], a1);
        a2 = DOT2(u2.p[e], w2[32 + 4 * i + e], a2);
        a3 = DOT2(u3.p[e], w2[48 + 4 * i + e], a3);
      }
    }
    p_lds[g][ch] = pv + ((a0 + a1) + (a2 + a3));
    __syncthreads();                               // B1: all p ready
    if (g == 0) {                                  // waves 0,1 only
      const float iv   = p_lds[0][ch];
      const float fv   = p_lds[1][ch];
      const float zraw = p_lds[2][ch];
      const float oraw = p_lds[3][ch];
      const float zv = 1.0f - 2.0f / (__expf(2.0f * zraw) + 1.0f);
      const float ov = 1.0f / (1.0f + __expf(-oraw));
      const float lf = fminf(fv, 0.0f) - __logf(1.0f + __expf(-fabsf(fv)));
      const float ft = lf + m;
      const float mn = fmaxf(ft, iv);
      const float is = __expf(iv - mn);
      const float fs = __expf(ft - mn);
      c = fs * c + is * zv;
      nrm = fs * nrm + is;
      m = mn;
      hv = ov * (c / nrm);
      h16[ch] = (_Float16)hv;                      // issue early; hides under shfl
      float s = hv, s2 = hv * hv;
      #pragma unroll
      for (int mm = 1; mm < 64; mm <<= 1) { s += __shfl_xor(s, mm); s2 += __shfl_xor(s2, mm); }
      if ((ch & 63) == 0) { red[(ch >> 6) * 2] = s; red[(ch >> 6) * 2 + 1] = s2; }
    }
    __syncthreads();                               // B2: h + red ready
    if (g == 0) {
      const float4 r = *(const float4*)red;        // broadcast
      const float S = r.x + r.z, S2 = r.y + r.w;
      const float mu = S * (1.0f / DPH);
      const float var = S2 * (1.0f / DPH) - mu * mu;
      const float rstd = rsqrtf(var + LN_EPS);
      yrow[(size_t)t * D_MODEL] = (hv - mu) * rstd * hw + hb + xv;
    }
    pv = pvn; xv = xvn;
  }
  if (g == 0) {
    state[bh * 128 + ch]         = c;
    state[8192  + bh * 128 + ch] = nrm;
    state[16384 + bh * 128 + ch] = m;
    state[24576 + bh * 128 + ch] = hv;
  }
}

// ------------------------------ FF1 (bf16 MFMA) ------------------------------
__global__ __launch_bounds__(256) void ff1_gemm(
    const float* __restrict__ y, const float* __restrict__ mu2,
    const float* __restrict__ rs2, const float* __restrict__ ln2w,
    const float* __restrict__ ln2b, const short* __restrict__ w1b,
    const float* __restrict__ b1, short* __restrict__ g, int row0) {
  __shared__ short As[128 * 64];
  __shared__ short Bs1[128 * 64];
  __shared__ short Bs2[128 * 64];
  const int tid = threadIdx.x;
  const int m0 = blockIdx.x * 128;
  const int n0 = blockIdx.y * 128;
  const int lane = tid & 63;
  const int wid = tid >> 6, wr = wid >> 1, wc = wid & 1;
  f32x4 acc1[4][4], acc2[4][4];
  #pragma unroll
  for (int i = 0; i < 4; ++i)
    #pragma unroll
    for (int j = 0; j < 4; ++j) { acc1[i][j] = (f32x4)0.0f; acc2[i][j] = (f32x4)0.0f; }
  for (int k0 = 0; k0 < D_MODEL; k0 += 64) {
    #pragma unroll
    for (int i = 0; i < 4; ++i) {
      const int cidx = tid + i * 256;
      const int r = cidx >> 3, c8 = cidx & 7;
      const int grow = row0 + m0 + r;
      const float* src = y + (size_t)grow * D_MODEL + k0 + c8 * 8;
      const float4 v0 = *(const float4*)src;
      const float4 v1 = *(const float4*)(src + 4);
      const float mu = mu2[grow], rs = rs2[grow];
      const float4 w0 = *(const float4*)(ln2w + k0 + c8 * 8);
      const float4 w1 = *(const float4*)(ln2w + k0 + c8 * 8 + 4);
      const float4 bb0 = *(const float4*)(ln2b + k0 + c8 * 8);
      const float4 bb1 = *(const float4*)(ln2b + k0 + c8 * 8 + 4);
      short8 s;
      s[0] = (short)f2bf((v0.x - mu) * rs * w0.x + bb0.x);
      s[1] = (short)f2bf((v0.y - mu) * rs * w0.y + bb0.y);
      s[2] = (short)f2bf((v0.z - mu) * rs * w0.z + bb0.z);
      s[3] = (short)f2bf((v0.w - mu) * rs * w0.w + bb0.w);
      s[4] = (short)f2bf((v1.x - mu) * rs * w1.x + bb1.x);
      s[5] = (short)f2bf((v1.y - mu) * rs * w1.y + bb1.y);
      s[6] = (short)f2bf((v1.z - mu) * rs * w1.z + bb1.z);
      s[7] = (short)f2bf((v1.w - mu) * rs * w1.w + bb1.w);
      *(short8*)&As[r * 64 + ((c8 ^ (r & 7)) << 3)] = s;
    }
    #pragma unroll
    for (int i = 0; i < 4; ++i) {
      const int cidx = tid + i * 256;
      const int r = cidx >> 3, c8 = cidx & 7;
      const short8 sv1 = *(const short8*)(w1b + (size_t)(n0 + r) * D_MODEL + k0 + c8 * 8);
      const short8 sv2 = *(const short8*)(w1b + (size_t)(DFF + n0 + r) * D_MODEL + k0 + c8 * 8);
      const int off = r * 64 + ((c8 ^ (r & 7)) << 3);
      *(short8*)&Bs1[off] = sv1;
      *(short8*)&Bs2[off] = sv2;
    }
    __syncthreads();
    #pragma unroll
    for (int ks = 0; ks < 2; ++ks) {
      short8 af[4], b1f[4], b2f[4];
      #pragma unroll
      for (int mf = 0; mf < 4; ++mf) {
        const int row = wr * 64 + mf * 16 + (lane & 15);
        const int c8 = ks * 4 + (lane >> 4);
        af[mf] = *(const short8*)&As[row * 64 + ((c8 ^ (row & 7)) << 3)];
      }
      #pragma unroll
      for (int nf = 0; nf < 4; ++nf) {
        const int row = wc * 64 + nf * 16 + (lane & 15);
        const int c8 = ks * 4 + (lane >> 4);
        const int off = row * 64 + ((c8 ^ (row & 7)) << 3);
        b1f[nf] = *(const short8*)&Bs1[off];
        b2f[nf] = *(const short8*)&Bs2[off];
      }
      #pragma unroll
      for (int mf = 0; mf < 4; ++mf)
        #pragma unroll
        for (int nf = 0; nf < 4; ++nf) {
          acc1[mf][nf] = __builtin_amdgcn_mfma_f32_16x16x32_bf16(af[mf], b1f[nf], acc1[mf][nf], 0, 0, 0);
          acc2[mf][nf] = __builtin_amdgcn_mfma_f32_16x16x32_bf16(af[mf], b2f[nf], acc2[mf][nf], 0, 0, 0);
        }
    }
    __syncthreads();
  }
  #pragma unroll
  for (int nf = 0; nf < 4; ++nf) {
    const int col = n0 + wc * 64 + nf * 16 + (lane & 15);
    const float bx1 = b1[col], bx2 = b1[DFF + col];
    #pragma unroll
    for (int mf = 0; mf < 4; ++mf) {
      const int rbase = m0 + wr * 64 + mf * 16 + ((lane >> 4) << 2);
      #pragma unroll
      for (int rr = 0; rr < 4; ++rr) {
        const float x1 = acc1[mf][nf][rr] + bx1;
        const float x2 = acc2[mf][nf][rr] + bx2;
        g[(size_t)(rbase + rr) * DFF + col] = (short)f2bf(x1 * gelu_exact(x2));
      }
    }
  }
}

// ----------------- FF2 (bf16 MFMA) + bias + residual, in place --------------
__global__ __launch_bounds__(256) void ff2_gemm(
    const short* __restrict__ g, const short* __restrict__ w2b,
    const float* __restrict__ b2, float* __restrict__ out, int row0) {
  __shared__ short As[128 * 64];
  __shared__ short Bs[128 * 64];
  const int tid = threadIdx.x;
  const int m0 = blockIdx.x * 128;
  const int n0 = blockIdx.y * 128;
  const int lane = tid & 63;
  const int wid = tid >> 6, wr = wid >> 1, wc = wid & 1;
  f32x4 acc[4][4];
  #pragma unroll
  for (int i = 0; i < 4; ++i)
    #pragma unroll
    for (int j = 0; j < 4; ++j) acc[i][j] = (f32x4)0.0f;
  for (int k0 = 0; k0 < DFF; k0 += 64) {
    #pragma unroll
    for (int i = 0; i < 4; ++i) {
      const int cidx = tid + i * 256;
      const int r = cidx >> 3, c8 = cidx & 7;
      const int off = r * 64 + ((c8 ^ (r & 7)) << 3);
      *(short8*)&As[off] = *(const short8*)(g + (size_t)(m0 + r) * DFF + k0 + c8 * 8);
      *(short8*)&Bs[off] = *(const short8*)(w2b + (size_t)(n0 + r) * DFF + k0 + c8 * 8);
    }
    __syncthreads();
    #pragma unroll
    for (int ks = 0; ks < 2; ++ks) {
      short8 af[4], bf[4];
      #pragma unroll
      for (int mf = 0; mf < 4; ++mf) {
        const int row = wr * 64 + mf * 16 + (lane & 15);
        const int c8 = ks * 4 + (lane >> 4);
        af[mf] = *(const short8*)&As[row * 64 + ((c8 ^ (row & 7)) << 3)];
      }
      #pragma unroll
      for (int nf = 0; nf < 4; ++nf) {
        const int row = wc * 64 + nf * 16 + (lane & 15);
        const int c8 = ks * 4 + (lane >> 4);
        bf[nf] = *(const short8*)&Bs[row * 64 + ((c8 ^ (row & 7)) << 3)];
      }
      #pragma unroll
      for (int mf = 0; mf < 4; ++mf)
        #pragma unroll
        for (int nf = 0; nf < 4; ++nf)
          acc[mf][nf] = __builtin_amdgcn_mfma_f32_16x16x32_bf16(af[mf], bf[nf], acc[mf][nf], 0, 0, 0);
    }
    __syncthreads();
  }
  #pragma unroll
  for (int nf = 0; nf < 4; ++nf) {
    const int col = n0 + wc * 64 + nf * 16 + (lane & 15);
    const float bias = b2[col];
    #pragma unroll
    for (int mf = 0; mf < 4; ++mf) {
      const int rbase = row0 + m0 + wr * 64 + mf * 16 + ((lane >> 4) << 2);
      #pragma unroll
      for (int rr = 0; rr < 4; ++rr) {
        float* p = out + (size_t)(rbase + rr) * D_MODEL + col;
        *p = acc[mf][nf][rr] + bias + *p;
      }
    }
  }
}

// ------------------------------- launcher -----------------------------------
extern "C" void kernel_launch(void* const* d_in, const int* in_sizes, int n_in,
                              void* d_out, int out_size, void* d_ws, size_t ws_size,
                              hipStream_t stream) {
  const float* x    = (const float*)d_in[0];
  const float* ihw  = (const float*)d_in[1];
  const float* ihb  = (const float*)d_in[2];
  const float* hhw  = (const float*)d_in[3];
  const float* ln1w = (const float*)d_in[4];
  const float* ln1b = (const float*)d_in[5];
  const float* hnw  = (const float*)d_in[6];
  const float* hnb  = (const float*)d_in[7];
  const float* ln2w = (const float*)d_in[8];
  const float* ln2b = (const float*)d_in[9];
  const float* ffw1 = (const float*)d_in[10];
  const float* ffb1 = (const float*)d_in[11];
  const float* ffw2 = (const float*)d_in[12];
  const float* ffb2 = (const float*)d_in[13];

  float* ws    = (float*)d_ws;
  float* r0    = ws;                    // 8388608 floats: proj fp32 / g bf16
  float* state = ws + 8388608;          // 32768
  float* mu1   = ws + 8421376;
  float* rs1   = ws + 8437760;
  float* mu2   = ws + 8454144;
  float* rs2   = ws + 8470528;
  short* w1b   = (short*)(ws + 8486912);   // 4096x1024 bf16 (8 MB)
  short* w2b   = (short*)(ws + 10584064);  // 1024x2048 bf16 (4 MB)
  h2f*   hh2   = (h2f*)(ws + 11632640);    // 64x512 packed f16 pairs (128 KB)
  short* gb    = (short*)r0;               // 8192x2048 bf16 chunk (32 MB)
  float* out   = (float*)d_out;

  cvt_w<<<dim3(4096 / 64, 1024 / 64), 256, 0, stream>>>(ffw1, w1b, 1024, 4096);
  cvt_w<<<dim3(1024 / 64, 2048 / 64), 256, 0, stream>>>(ffw2, w2b, 2048, 1024);
  cvt_hh<<<128, 256, 0, stream>>>(hhw, hh2);
  ln_stats_kernel<<<NROWS, 256, 0, stream>>>(x, mu1, rs1);
  for (int cidx = 0; cidx < SEQ / CHUNK_L; ++cidx) {
    const int l0 = cidx * CHUNK_L;
    proj_gemm<<<dim3(CHUNK_L * BATCH / 64, 512 / 128, NHEAD), 256, 0, stream>>>(
        x, mu1, rs1, ln1w, ln1b, ihw, ihb, r0, l0);
    scan_chunk<<<BATCH * NHEAD, 512, 0, stream>>>(r0, hh2, x, hnw, hnb, state, out, l0);
  }
  ln_stats_kernel<<<NROWS, 256, 0, stream>>>(out, mu2, rs2);
  for (int rc = 0; rc < NROWS / ROWCH; ++rc) {
    const int row0 = rc * ROWCH;
    ff1_gemm<<<dim3(ROWCH / 128, DFF / 128), 256, 0, stream>>>(
        out, mu2, rs2, ln2w, ln2b, w1b, ffb1, gb, row0);
    ff2_gemm<<<dim3(ROWCH / 128, D_MODEL / 128), 256, 0, stream>>>(
        gb, w2b, ffb2, out, row0);
  }
}